// Round 3
// baseline (219.051 us; speedup 1.0000x reference)
//
#include <hip/hip_runtime.h>
#include <hip/hip_fp16.h>

#define B_ 1024
#define L_ 1024
#define NCAT_ 20
#define NNUM_ 10
#define E_ 32
#define A_ 128
#define H_ 256
#define TOPK_ 30
#define INV_SQRT_A 0.08838834764831845f

typedef _Float16 half8 __attribute__((ext_vector_type(8)));
typedef float f32x4 __attribute__((ext_vector_type(4)));

// monotonic float<->u32 (roundtrip exact)
__device__ __forceinline__ unsigned sortable(float f) {
    unsigned u = __float_as_uint(f);
    return (u & 0x80000000u) ? ~u : (u | 0x80000000u);
}
__device__ __forceinline__ float unsortable(unsigned s) {
    unsigned u = (s & 0x80000000u) ? (s ^ 0x80000000u) : ~s;
    return __uint_as_float(u);
}
__device__ __forceinline__ half8 cvt_h8(const float4 u, const float4 v) {
    half8 a;
    a[0] = (_Float16)u.x; a[1] = (_Float16)u.y;
    a[2] = (_Float16)u.z; a[3] = (_Float16)u.w;
    a[4] = (_Float16)v.x; a[5] = (_Float16)v.y;
    a[6] = (_Float16)v.z; a[7] = (_Float16)v.w;
    return a;
}

// ---------------------------------------------------------------------------
// K1: prep + M + weight transpose-convert.  R13: the 1024 seq_emb-conversion
// blocks are GONE (Phase A reads f32 seq_emb straight from L2/L3).  Grid 332.
// blk <256: per-4-row prep.  256..259: M = Wv@Wo (+ zero group counters).
// 260..331: transposed f16 weights WT[n][k] for the MFMA MLP.
// ---------------------------------------------------------------------------
#define K1_GRID 332
__global__ __launch_bounds__(256) void fused_prep_kernel(
    const int* __restrict__ cats, const float* __restrict__ nums,
    const int* __restrict__ tgt_ids, const float* __restrict__ cat_emb,
    const float* __restrict__ Wnum, const float* __restrict__ bnum,
    const float* __restrict__ Wq, const float* __restrict__ Wk,
    const float* __restrict__ Wv, const float* __restrict__ Wo,
    const float* __restrict__ Wpool, const float* __restrict__ bpool,
    const float* __restrict__ Wmlp,
    const float* __restrict__ q1W1, const float* __restrict__ q1W2,
    const float* __restrict__ q1Wp,
    const float* __restrict__ q2W1, const float* __restrict__ q2W2,
    const float* __restrict__ q2Wp,
    float* __restrict__ p_out, float* __restrict__ fused, float* __restrict__ M,
    int* __restrict__ cnt,
    __half* __restrict__ WmlpT,
    __half* __restrict__ W1T1, __half* __restrict__ W2T1, __half* __restrict__ WpT1,
    __half* __restrict__ W1T2, __half* __restrict__ W2T2, __half* __restrict__ WpT2)
{
    const int blk = blockIdx.x;
    const int t = threadIdx.x;

    if (blk < 256) {
        __shared__ float ce[4][NCAT_ * E_];
        __shared__ float tg[4][E_];
        __shared__ float nm[4][NNUM_];
        __shared__ float qs[4][A_];
        __shared__ float part[8][4][E_];
        const int r0 = blk * 4;

        for (int idx = t; idx < 640; idx += 256) {
            const int q = idx >> 3, f4 = idx & 7;
            const int row = q / 20, cat = q % 20;
            const int tok = cats[(r0 + row) * NCAT_ + cat];
            ((float4*)&ce[row][cat * 32])[f4] =
                ((const float4*)(cat_emb + (size_t)tok * 32))[f4];
        }
        if (t < 32) {
            const int row = t >> 3, f4 = t & 7;
            const int tok = tgt_ids[r0 + row];
            ((float4*)&tg[row][0])[f4] =
                ((const float4*)(cat_emb + (size_t)tok * 32))[f4];
        }
        if (t >= 64 && t < 104) {
            const int x = t - 64;
            nm[x / 10][x % 10] = nums[(x / 10) * 0 + (r0 + x / 10) * NNUM_ + x % 10];
        }
        __syncthreads();

        {
            const int w = t >> 6, lane = t & 63;
            float q0 = 0.f, q1 = 0.f;
#pragma unroll
            for (int e = 0; e < E_; ++e) {
                float te = tg[w][e];
                q0 += te * Wq[e * A_ + lane];
                q1 += te * Wq[e * A_ + lane + 64];
            }
            qs[w][lane] = q0; qs[w][lane + 64] = q1;
        }

        {
            const int iseg = t >> 5;
            const int row = (t >> 3) & 3;
            const int c0 = (t & 7) * 4;
            float4 acc = make_float4(0.f, 0.f, 0.f, 0.f);
            const int i0 = iseg * 80;
            for (int i = i0; i < i0 + 80; ++i) {
                float4 wv = *(const float4*)(Wpool + i * 32 + c0);
                acc.x += ce[row][i] * wv.x; acc.y += ce[row][i] * wv.y;
                acc.z += ce[row][i] * wv.z; acc.w += ce[row][i] * wv.w;
            }
            *(float4*)&part[iseg][row][c0] = acc;
        }
        __syncthreads();

        if (t < 128) {
            const int row = t >> 5, c = t & 31;
            const int b = r0 + row;
            float s = bpool[c];
#pragma unroll
            for (int g = 0; g < 8; ++g) s += part[g][row][c];
            fused[b * 128 + 64 + c] = s;
            fused[b * 128 + c] = tg[row][c];

            float ne = bnum[c];
#pragma unroll
            for (int n = 0; n < NNUM_; ++n) ne += nm[row][n] * Wnum[n * 32 + c];
            fused[b * 128 + 96 + c] = ne;

            float pv = 0.f;
#pragma unroll 8
            for (int a = 0; a < A_; ++a) pv += Wk[c * A_ + a] * qs[row][a];
            p_out[b * 32 + c] = pv;
        }
        return;
    }

    if (blk < 260) {
        if (blk == 256 && t < 64) cnt[t] = 0;   // group counters for K2
        const int o = (blk - 256) * 256 + t;
        const int j = o >> 5, e = o & 31;
        float sm = 0.f;
#pragma unroll 8
        for (int a = 0; a < A_; ++a) sm += Wv[j * A_ + a] * Wo[a * E_ + e];
        M[o] = sm;
        return;
    }

    // ---- transpose-convert weights to [n][k] f16 (blocks 260..331)
    {
        int c = (blk - 260) * 256 + t;           // 0 .. 18431
        for (; c < 53248; c += 72 * 256) {
            const float* src; __half* dst;
            int n, k0, K;
            if (c < 4096) {
                n = c >> 4; k0 = (c & 15) << 3; K = 128;
                src = Wmlp; dst = WmlpT;
            } else {
                const int c2 = c - 4096;
                const int m = c2 >> 13, idx = c2 & 8191;
                n = idx >> 5; k0 = (idx & 31) << 3; K = 256;
                switch (m) {
                    case 0: src = q1W1; dst = W1T1; break;
                    case 1: src = q1W2; dst = W2T1; break;
                    case 2: src = q1Wp; dst = WpT1; break;
                    case 3: src = q2W1; dst = W1T2; break;
                    case 4: src = q2W2; dst = W2T2; break;
                    default: src = q2Wp; dst = WpT2; break;
                }
            }
            float v[8];
#pragma unroll
            for (int i = 0; i < 8; ++i) v[i] = src[(size_t)(k0 + i) * 256 + n];
            float4 wq;
            __half2* hp = (__half2*)&wq;
            hp[0] = __float22half2_rn(make_float2(v[0], v[1]));
            hp[1] = __float22half2_rn(make_float2(v[2], v[3]));
            hp[2] = __float22half2_rn(make_float2(v[4], v[5]));
            hp[3] = __float22half2_rn(make_float2(v[6], v[7]));
            *(float4*)(dst + (size_t)n * K + k0) = wq;
        }
    }
}

// ---------------------------------------------------------------------------
// K2: scores (f32 gathers) + top-30 + softmax + interest, RM=4 grid 256
// (R10-proven phase A/B shape), THEN last-man-out MFMA MLP: each block
// atomicAdds its 4-block group counter; the 4th arriver runs the 16-row
// MLP+QNN chain via v_mfma_f32_16x16x32_f16.  Device-scope fences pair the
// interest stores with the counter (Guideline 16); no spin-waits.
// ---------------------------------------------------------------------------
#define RM 4
#define GR 16
#define HSP 260
#define TSP 264
__global__ __launch_bounds__(512) void score_mlp_kernel(
    const int* __restrict__ seqs, const float* __restrict__ seq_emb,
    const float* __restrict__ p, const float* __restrict__ M,
    const float* __restrict__ bo, float* __restrict__ fused,
    int* __restrict__ cnt,
    const __half* __restrict__ WmlpT, const float* __restrict__ bmlp,
    const __half* __restrict__ W1T1, const __half* __restrict__ W2T1,
    const __half* __restrict__ WpT1,
    const float* __restrict__ b11, const float* __restrict__ b12,
    const float* __restrict__ b1p,
    const __half* __restrict__ W1T2, const __half* __restrict__ W2T2,
    const __half* __restrict__ WpT2,
    const float* __restrict__ b21, const float* __restrict__ b22,
    const float* __restrict__ b2p,
    const float* __restrict__ Wout, const float* __restrict__ bout,
    float* __restrict__ out)
{
    const int b0 = blockIdx.x * RM;
    const int tid = threadIdx.x;

    __shared__ float sc[RM][L_];          // 16 KB (score rows; reused as ebar)
    __shared__ float ps[RM][E_];
    __shared__ float sw[RM][32];
    __shared__ int   stok[RM][32];
    __shared__ float hs[GR][HSP];
    __shared__ __half ts_h[GR][TSP];
    __shared__ int doml;

    if (tid < RM * 32)
        ps[tid >> 5][tid & 31] = p[(b0 + (tid >> 5)) * 32 + (tid & 31)];
    __syncthreads();

    // ---- Phase A: scores, f32 gathers. 128 threads/row, 8 tokens/thread
    {
        const int row = tid >> 7;
        const int s = tid & 127;
        const int base = (b0 + row) * L_;
#pragma unroll
        for (int jj = 0; jj < 4; ++jj) {
            const int l1 = jj * 128 + s;
            const int l2 = l1 + 512;
            const int tok1 = seqs[base + l1];
            const int tok2 = seqs[base + l2];
            const float4* r1 = (const float4*)(seq_emb + (size_t)tok1 * 32);
            const float4* r2 = (const float4*)(seq_emb + (size_t)tok2 * 32);
            float4 bufA[8], bufB[8];
#pragma unroll
            for (int i = 0; i < 8; ++i) bufA[i] = r1[i];
#pragma unroll
            for (int i = 0; i < 8; ++i) bufB[i] = r2[i];
            float a0 = 0.f, a1 = 0.f;
#pragma unroll
            for (int i = 0; i < 8; ++i) {
                a0 += bufA[i].x * ps[row][4 * i]     + bufA[i].y * ps[row][4 * i + 1]
                    + bufA[i].z * ps[row][4 * i + 2] + bufA[i].w * ps[row][4 * i + 3];
                a1 += bufB[i].x * ps[row][4 * i]     + bufB[i].y * ps[row][4 * i + 1]
                    + bufB[i].z * ps[row][4 * i + 2] + bufB[i].w * ps[row][4 * i + 3];
            }
            sc[row][l1] = a0 * INV_SQRT_A;
            sc[row][l2] = a1 * INV_SQRT_A;
        }
    }
    __syncthreads();

    // ---- Phase B: selection, one row per wave (waves 0-3). R9-proven.
    if (tid < RM * 64) {
        const int w = tid >> 6;
        const int lane = tid & 63;
        const int bb = b0 + w;

        unsigned long long key[16];
#pragma unroll
        for (int j = 0; j < 16; ++j) {
            const int l = j * 64 + lane;
            key[j] = ((unsigned long long)sortable(sc[w][l]) << 10)
                   | (unsigned)(1023 - l);
        }
#pragma unroll
        for (int a = 0; a < 15; ++a)
#pragma unroll
            for (int j = 0; j < 15 - a; ++j) {
                const bool swp = key[j] < key[j + 1];
                const unsigned long long hi = swp ? key[j + 1] : key[j];
                const unsigned long long lo = swp ? key[j] : key[j + 1];
                key[j] = hi; key[j + 1] = lo;
            }

        float myv = -1e30f; int myl = 0;
        unsigned long long front = key[0];
        for (int k = 0; k < TOPK_; ++k) {
            unsigned long long wk = front;
#pragma unroll
            for (int off = 32; off > 0; off >>= 1) {
                unsigned long long o = __shfl_xor(wk, off);
                if (o > wk) wk = o;
            }
            if (lane == k) {
                myv = unsortable((unsigned)(wk >> 10));
                myl = 1023 - (int)(wk & 1023);
            }
            if (front == wk) {
#pragma unroll
                for (int j = 0; j < 15; ++j) key[j] = key[j + 1];
                key[15] = 0ULL;
                front = key[0];
            }
        }

        float m = myv;
#pragma unroll
        for (int off = 32; off > 0; off >>= 1) m = fmaxf(m, __shfl_xor(m, off));
        float e = (lane < TOPK_) ? expf(myv - m) : 0.f;
        float s = e;
#pragma unroll
        for (int off = 32; off > 0; off >>= 1) s += __shfl_xor(s, off);
        if (lane < TOPK_) {
            sw[w][lane]   = e / s;
            stok[w][lane] = seqs[bb * L_ + myl];
        }

        if (lane < E_) {
            float acc = 0.f;
#pragma unroll
            for (int k = 0; k < TOPK_; ++k)
                acc += sw[w][k] * seq_emb[(size_t)stok[w][k] * 32 + lane];
            sc[w][lane] = acc;   // ebar (sc row free now; same-wave r/w)
        }
        if (lane < E_) {
            float acc = bo[lane];
#pragma unroll
            for (int j = 0; j < E_; ++j) acc += sc[w][j] * M[j * E_ + lane];
            fused[bb * 128 + 32 + lane] = acc;   // interest -> global
        }
    }
    __syncthreads();          // all interest stores issued (block-wide)

    // ---- last-man-out: 4th block of the 4-block group runs the 16-row MLP
    if (tid == 0) {
        __threadfence();      // publish this block's fused stores (L2 wb)
        const int g = blockIdx.x >> 2;
        const int old = atomicAdd(&cnt[g], 1);
        doml = (old == 3) ? 1 : 0;
        if (old == 3) __threadfence();   // acquire: invalidate stale caches
    }
    __syncthreads();
    if (!doml) return;

    // ================= MFMA MLP for rows r0m .. r0m+15 =================
    const int r0m = (blockIdx.x >> 2) * GR;
    const int w = tid >> 6;
    const int l = tid & 63;
    const int lr = l & 15;
    const int lk = l >> 4;
    const int n0 = w * 32;

    f32x4 hC0, hC1;
    const f32x4 zf = {0.f, 0.f, 0.f, 0.f};

    // ---- stage 1: h = relu(x @ Wmlp + bmlp), K = 128
    {
        half8 ax[4];
        const float* xrow = fused + (size_t)(r0m + lr) * 128 + lk * 8;
#pragma unroll
        for (int ks = 0; ks < 4; ++ks) {
            float4 u = *(const float4*)(xrow + ks * 32);
            float4 v = *(const float4*)(xrow + ks * 32 + 4);
            ax[ks] = cvt_h8(u, v);
        }
#pragma unroll
        for (int t = 0; t < 2; ++t) {
            f32x4 c = zf;
            const __half* wb = WmlpT + (size_t)(n0 + 16 * t + lr) * 128 + lk * 8;
#pragma unroll
            for (int ks = 0; ks < 4; ++ks) {
                half8 b = *(const half8*)(wb + ks * 32);
                c = __builtin_amdgcn_mfma_f32_16x16x32_f16(ax[ks], b, c, 0, 0, 0);
            }
            const int j = n0 + 16 * t + lr;
            const float bm = bmlp[j];
#pragma unroll
            for (int r = 0; r < 4; ++r) {
                float vv = fmaxf(c[r] + bm, 0.f);
                if (t == 0) hC0[r] = vv; else hC1[r] = vv;
                hs[4 * lk + r][j] = vv;
            }
        }
    }
    __syncthreads();

    // ---- 2 qnn blocks
#pragma unroll
    for (int q = 0; q < 2; ++q) {
        const __half* W1T = q ? W1T2 : W1T1;
        const __half* W2T = q ? W2T2 : W2T1;
        const __half* WpT = q ? WpT2 : WpT1;
        const float* bb1 = q ? b21 : b11;
        const float* bb2 = q ? b22 : b12;
        const float* bbp = q ? b2p : b1p;

        half8 ah[8];
#pragma unroll
        for (int ks = 0; ks < 8; ++ks) {
            const float* hr = &hs[lr][ks * 32 + lk * 8];
            float4 u = *(const float4*)hr;
            float4 v = *(const float4*)(hr + 4);
            ah[ks] = cvt_h8(u, v);
        }
#pragma unroll
        for (int t = 0; t < 2; ++t) {
            f32x4 t1 = zf, t2 = zf;
            const __half* w1 = W1T + (size_t)(n0 + 16 * t + lr) * 256 + lk * 8;
            const __half* w2 = W2T + (size_t)(n0 + 16 * t + lr) * 256 + lk * 8;
#pragma unroll
            for (int ks = 0; ks < 8; ++ks) {
                half8 b1 = *(const half8*)(w1 + ks * 32);
                t1 = __builtin_amdgcn_mfma_f32_16x16x32_f16(ah[ks], b1, t1, 0, 0, 0);
                half8 b2 = *(const half8*)(w2 + ks * 32);
                t2 = __builtin_amdgcn_mfma_f32_16x16x32_f16(ah[ks], b2, t2, 0, 0, 0);
            }
            const int j = n0 + 16 * t + lr;
            const float v1 = bb1[j], v2 = bb2[j];
#pragma unroll
            for (int r = 0; r < 4; ++r) {
                float tv = (t1[r] + v1) * (t2[r] + v2);
                ts_h[4 * lk + r][j] = __float2half_rn(tv);
            }
        }
        __syncthreads();

        half8 pa[8];
#pragma unroll
        for (int ks = 0; ks < 8; ++ks)
            pa[ks] = *(const half8*)&ts_h[lr][ks * 32 + lk * 8];
#pragma unroll
        for (int t = 0; t < 2; ++t) {
            f32x4 c = (t == 0) ? hC0 : hC1;
            const __half* wp = WpT + (size_t)(n0 + 16 * t + lr) * 256 + lk * 8;
#pragma unroll
            for (int ks = 0; ks < 8; ++ks) {
                half8 b = *(const half8*)(wp + ks * 32);
                c = __builtin_amdgcn_mfma_f32_16x16x32_f16(pa[ks], b, c, 0, 0, 0);
            }
            const int j = n0 + 16 * t + lr;
            const float bp = bbp[j];
#pragma unroll
            for (int r = 0; r < 4; ++r) {
                float vv = c[r] + bp;
                if (t == 0) hC0[r] = vv; else hC1[r] = vv;
                hs[4 * lk + r][j] = vv;
            }
        }
        __syncthreads();
    }

    // ---- out = hs @ Wout + bout : 32 threads per row, 8 cols each
    {
        const int i = tid >> 5;
        const int seg = tid & 31;
        const int cb = seg * 8;
        float psum = 0.f;
#pragma unroll
        for (int u = 0; u < 8; ++u) psum += hs[i][cb + u] * Wout[cb + u];
#pragma unroll
        for (int off = 16; off > 0; off >>= 1) psum += __shfl_xor(psum, off);
        if (seg == 0) out[r0m + i] = psum + bout[0];
    }
}

// ---------------------------------------------------------------------------
extern "C" void kernel_launch(void* const* d_in, const int* in_sizes, int n_in,
                              void* d_out, int out_size, void* d_ws, size_t ws_size,
                              hipStream_t stream) {
    const int*   cats    = (const int*)d_in[0];
    const float* nums    = (const float*)d_in[1];
    const int*   seqs    = (const int*)d_in[2];
    const int*   tgt_ids = (const int*)d_in[3];
    const float* cat_emb = (const float*)d_in[4];
    const float* seq_emb = (const float*)d_in[5];
    const float* Wnum    = (const float*)d_in[6];
    const float* bnum    = (const float*)d_in[7];
    const float* Wq      = (const float*)d_in[8];
    const float* Wk      = (const float*)d_in[9];
    const float* Wv      = (const float*)d_in[10];
    const float* Wo      = (const float*)d_in[11];
    const float* bo      = (const float*)d_in[12];
    const float* Wpool   = (const float*)d_in[13];
    const float* bpool   = (const float*)d_in[14];
    const float* Wmlp    = (const float*)d_in[15];
    const float* bmlp    = (const float*)d_in[16];
    const float* q1_W1   = (const float*)d_in[17];
    const float* q1_b1   = (const float*)d_in[18];
    const float* q1_W2   = (const float*)d_in[19];
    const float* q1_b2   = (const float*)d_in[20];
    const float* q1_Wp   = (const float*)d_in[21];
    const float* q1_bp   = (const float*)d_in[22];
    const float* q2_W1   = (const float*)d_in[23];
    const float* q2_b1   = (const float*)d_in[24];
    const float* q2_W2   = (const float*)d_in[25];
    const float* q2_b2   = (const float*)d_in[26];
    const float* q2_Wp   = (const float*)d_in[27];
    const float* q2_bp   = (const float*)d_in[28];
    const float* Wout    = (const float*)d_in[29];
    const float* bout    = (const float*)d_in[30];

    // Workspace layout (float-slot offsets); __half pairs pack 2/slot.
    float* ws = (float*)d_ws;
    float*   p       = ws;                         //      0 .. 32768
    float*   fused   = ws + 32768;                 //  32768 .. 163840
    float*   M       = ws + 163840;                // 163840 .. 164864
    int*     cnt     = (int*)(ws + 164864);        // 164864 .. 164928 (64)
    __half*  WmlpT   = (__half*)(ws + 164928);     // 164928 .. 181312 (32768 h)
    __half*  W1T1    = (__half*)(ws + 181312);     // 181312 .. 214080 (65536 h)
    __half*  W2T1    = (__half*)(ws + 214080);     // 214080 .. 246848
    __half*  WpT1    = (__half*)(ws + 246848);     // 246848 .. 279616
    __half*  W1T2    = (__half*)(ws + 279616);     // 279616 .. 312384
    __half*  W2T2    = (__half*)(ws + 312384);     // 312384 .. 345152
    __half*  WpT2    = (__half*)(ws + 345152);     // 345152 .. 377920

    float* out = (float*)d_out;

    fused_prep_kernel<<<K1_GRID, 256, 0, stream>>>(
        cats, nums, tgt_ids, cat_emb, Wnum, bnum, Wq, Wk, Wv, Wo,
        Wpool, bpool, Wmlp,
        q1_W1, q1_W2, q1_Wp, q2_W1, q2_W2, q2_Wp,
        p, fused, M, cnt,
        WmlpT, W1T1, W2T1, WpT1, W1T2, W2T2, WpT2);

    score_mlp_kernel<<<B_ / RM, 512, 0, stream>>>(
        seqs, seq_emb, p, M, bo, fused, cnt,
        WmlpT, bmlp,
        W1T1, W2T1, WpT1, q1_b1, q1_b2, q1_bp,
        W1T2, W2T2, WpT2, q2_b1, q2_b2, q2_bp,
        Wout, bout, out);
}

// Round 4
// 199.286 us; speedup vs baseline: 1.0992x; 1.0992x over previous
//
#include <hip/hip_runtime.h>
#include <hip/hip_fp16.h>

#define B_ 1024
#define L_ 1024
#define NCAT_ 20
#define NNUM_ 10
#define E_ 32
#define A_ 128
#define H_ 256
#define TOPK_ 30
#define INV_SQRT_A 0.08838834764831845f

typedef _Float16 half8 __attribute__((ext_vector_type(8)));
typedef float f32x4 __attribute__((ext_vector_type(4)));

// monotonic float<->u32 (roundtrip exact)
__device__ __forceinline__ unsigned sortable(float f) {
    unsigned u = __float_as_uint(f);
    return (u & 0x80000000u) ? ~u : (u | 0x80000000u);
}
__device__ __forceinline__ float unsortable(unsigned s) {
    unsigned u = (s & 0x80000000u) ? (s ^ 0x80000000u) : ~s;
    return __uint_as_float(u);
}
__device__ __forceinline__ half8 cvt_h8(const float4 u, const float4 v) {
    half8 a;
    a[0] = (_Float16)u.x; a[1] = (_Float16)u.y;
    a[2] = (_Float16)u.z; a[3] = (_Float16)u.w;
    a[4] = (_Float16)v.x; a[5] = (_Float16)v.y;
    a[6] = (_Float16)v.z; a[7] = (_Float16)v.w;
    return a;
}

// ---------------------------------------------------------------------------
// K1: prep + seq f16 conversion + M + weight transpose.  Grid 1356 (as R0).
//  blk <  256 : per-4-row prep (fused cols 0-31/64-127, p = q@Wk^T)
//  blk < 1280 : seq_emb -> f16 (3.2 MB table => L2-resident gathers in K2;
//               R13 proved f32 gathers thrash the 4 MB/XCD L2: FETCH 20->69MB)
//  blk < 1284 : M = Wv@Wo fold (+ zero group counters)
//  blk < 1356 : transposed f16 weights WT[n][k] for the MFMA MLP
// ---------------------------------------------------------------------------
#define K1_GRID 1356
__global__ __launch_bounds__(256) void fused_prep_kernel(
    const int* __restrict__ cats, const float* __restrict__ nums,
    const int* __restrict__ tgt_ids, const float* __restrict__ cat_emb,
    const float* __restrict__ Wnum, const float* __restrict__ bnum,
    const float* __restrict__ Wq, const float* __restrict__ Wk,
    const float* __restrict__ Wv, const float* __restrict__ Wo,
    const float* __restrict__ Wpool, const float* __restrict__ bpool,
    const float* __restrict__ seq_emb, const float* __restrict__ Wmlp,
    const float* __restrict__ q1W1, const float* __restrict__ q1W2,
    const float* __restrict__ q1Wp,
    const float* __restrict__ q2W1, const float* __restrict__ q2W2,
    const float* __restrict__ q2Wp,
    float* __restrict__ p_out, float* __restrict__ fused, float* __restrict__ M,
    int* __restrict__ cnt, __half2* __restrict__ seq_h2,
    __half* __restrict__ WmlpT,
    __half* __restrict__ W1T1, __half* __restrict__ W2T1, __half* __restrict__ WpT1,
    __half* __restrict__ W1T2, __half* __restrict__ W2T2, __half* __restrict__ WpT2)
{
    const int blk = blockIdx.x;
    const int t = threadIdx.x;

    if (blk < 256) {
        __shared__ float ce[4][NCAT_ * E_];
        __shared__ float tg[4][E_];
        __shared__ float nm[4][NNUM_];
        __shared__ float qs[4][A_];
        __shared__ float part[8][4][E_];
        const int r0 = blk * 4;

        for (int idx = t; idx < 640; idx += 256) {
            const int q = idx >> 3, f4 = idx & 7;
            const int row = q / 20, cat = q % 20;
            const int tok = cats[(r0 + row) * NCAT_ + cat];
            ((float4*)&ce[row][cat * 32])[f4] =
                ((const float4*)(cat_emb + (size_t)tok * 32))[f4];
        }
        if (t < 32) {
            const int row = t >> 3, f4 = t & 7;
            const int tok = tgt_ids[r0 + row];
            ((float4*)&tg[row][0])[f4] =
                ((const float4*)(cat_emb + (size_t)tok * 32))[f4];
        }
        if (t >= 64 && t < 104) {
            const int x = t - 64;
            nm[x / 10][x % 10] = nums[(r0 + x / 10) * NNUM_ + x % 10];
        }
        __syncthreads();

        {
            const int w = t >> 6, lane = t & 63;
            float q0 = 0.f, q1 = 0.f;
#pragma unroll
            for (int e = 0; e < E_; ++e) {
                float te = tg[w][e];
                q0 += te * Wq[e * A_ + lane];
                q1 += te * Wq[e * A_ + lane + 64];
            }
            qs[w][lane] = q0; qs[w][lane + 64] = q1;
        }

        {
            const int iseg = t >> 5;
            const int row = (t >> 3) & 3;
            const int c0 = (t & 7) * 4;
            float4 acc = make_float4(0.f, 0.f, 0.f, 0.f);
            const int i0 = iseg * 80;
            for (int i = i0; i < i0 + 80; ++i) {
                float4 wv = *(const float4*)(Wpool + i * 32 + c0);
                acc.x += ce[row][i] * wv.x; acc.y += ce[row][i] * wv.y;
                acc.z += ce[row][i] * wv.z; acc.w += ce[row][i] * wv.w;
            }
            *(float4*)&part[iseg][row][c0] = acc;
        }
        __syncthreads();

        if (t < 128) {
            const int row = t >> 5, c = t & 31;
            const int b = r0 + row;
            float s = bpool[c];
#pragma unroll
            for (int g = 0; g < 8; ++g) s += part[g][row][c];
            fused[b * 128 + 64 + c] = s;
            fused[b * 128 + c] = tg[row][c];

            float ne = bnum[c];
#pragma unroll
            for (int n = 0; n < NNUM_; ++n) ne += nm[row][n] * Wnum[n * 32 + c];
            fused[b * 128 + 96 + c] = ne;

            float pv = 0.f;
#pragma unroll 8
            for (int a = 0; a < A_; ++a) pv += Wk[c * A_ + a] * qs[row][a];
            p_out[b * 32 + c] = pv;
        }
        return;
    }

    if (blk < 1280) {
        int x = (blk - 256) * 256 + t;
        for (; x < 800016; x += 1024 * 256) {
            float2 v = ((const float2*)seq_emb)[x];
            seq_h2[x] = __float22half2_rn(v);
        }
        return;
    }

    if (blk < 1284) {
        if (blk == 1280 && t < 64) cnt[t] = 0;   // group counters for K2
        const int o = (blk - 1280) * 256 + t;
        const int j = o >> 5, e = o & 31;
        float sm = 0.f;
#pragma unroll 8
        for (int a = 0; a < A_; ++a) sm += Wv[j * A_ + a] * Wo[a * E_ + e];
        M[o] = sm;
        return;
    }

    // ---- transpose-convert weights to [n][k] f16 (blocks 1284..1355)
    {
        int c = (blk - 1284) * 256 + t;           // 0 .. 18431
        for (; c < 53248; c += 72 * 256) {
            const float* src; __half* dst;
            int n, k0, K;
            if (c < 4096) {
                n = c >> 4; k0 = (c & 15) << 3; K = 128;
                src = Wmlp; dst = WmlpT;
            } else {
                const int c2 = c - 4096;
                const int m = c2 >> 13, idx = c2 & 8191;
                n = idx >> 5; k0 = (idx & 31) << 3; K = 256;
                switch (m) {
                    case 0: src = q1W1; dst = W1T1; break;
                    case 1: src = q1W2; dst = W2T1; break;
                    case 2: src = q1Wp; dst = WpT1; break;
                    case 3: src = q2W1; dst = W1T2; break;
                    case 4: src = q2W2; dst = W2T2; break;
                    default: src = q2Wp; dst = WpT2; break;
                }
            }
            float v[8];
#pragma unroll
            for (int i = 0; i < 8; ++i) v[i] = src[(size_t)(k0 + i) * 256 + n];
            float4 wq;
            __half2* hp = (__half2*)&wq;
            hp[0] = __float22half2_rn(make_float2(v[0], v[1]));
            hp[1] = __float22half2_rn(make_float2(v[2], v[3]));
            hp[2] = __float22half2_rn(make_float2(v[4], v[5]));
            hp[3] = __float22half2_rn(make_float2(v[6], v[7]));
            *(float4*)(dst + (size_t)n * K + k0) = wq;
        }
    }
}

// ---------------------------------------------------------------------------
// K2: scores (f16 gathers, R0-proven) + top-30 + softmax + interest, RM=4
// grid 256, THEN last-man-out MFMA MLP (R13-proven): each block atomicAdds
// its 4-block group counter; the 4th arriver runs the 16-row MLP+QNN chain
// via v_mfma_f32_16x16x32_f16.  Replaces R0's ~25 us VALU-bound GEMV chain.
// ---------------------------------------------------------------------------
#define RM 4
#define GR 16
#define HSP 260
#define TSP 264
__global__ __launch_bounds__(512) void score_mlp_kernel(
    const int* __restrict__ seqs, const __half* __restrict__ seq_h,
    const float* __restrict__ seq_emb, const float* __restrict__ p,
    const float* __restrict__ M, const float* __restrict__ bo,
    float* __restrict__ fused, int* __restrict__ cnt,
    const __half* __restrict__ WmlpT, const float* __restrict__ bmlp,
    const __half* __restrict__ W1T1, const __half* __restrict__ W2T1,
    const __half* __restrict__ WpT1,
    const float* __restrict__ b11, const float* __restrict__ b12,
    const float* __restrict__ b1p,
    const __half* __restrict__ W1T2, const __half* __restrict__ W2T2,
    const __half* __restrict__ WpT2,
    const float* __restrict__ b21, const float* __restrict__ b22,
    const float* __restrict__ b2p,
    const float* __restrict__ Wout, const float* __restrict__ bout,
    float* __restrict__ out)
{
    const int b0 = blockIdx.x * RM;
    const int tid = threadIdx.x;

    __shared__ float sc[RM][L_];          // 16 KB (score rows; reused as ebar)
    __shared__ float ps[RM][E_];
    __shared__ float sw[RM][32];
    __shared__ int   stok[RM][32];
    __shared__ float hs[GR][HSP];         // MFMA MLP activations (f32)
    __shared__ __half ts_h[GR][TSP];      // quad term (f16)
    __shared__ int doml;

    if (tid < RM * 32)
        ps[tid >> 5][tid & 31] = p[(b0 + (tid >> 5)) * 32 + (tid & 31)];
    __syncthreads();

    // ---- Phase A: scores (f16 table, L2-resident). 128 thr/row, 8 tok/thr
    {
        const int row = tid >> 7;
        const int s = tid & 127;
        const int bb = b0 + row;
#pragma unroll
        for (int jj = 0; jj < 4; ++jj) {
            const int l1 = jj * 256 + s;
            const int l2 = l1 + 128;
            const int tok1 = seqs[bb * L_ + l1];
            const int tok2 = seqs[bb * L_ + l2];
            float4 buf[2][4];
            const float4* r1 = (const float4*)(seq_h + (size_t)tok1 * 32);
            const float4* r2 = (const float4*)(seq_h + (size_t)tok2 * 32);
#pragma unroll
            for (int i = 0; i < 4; ++i) buf[0][i] = r1[i];
#pragma unroll
            for (int i = 0; i < 4; ++i) buf[1][i] = r2[i];

            float acc0 = 0.f, acc1 = 0.f;
#pragma unroll
            for (int i = 0; i < 4; ++i) {
                const __half2* h1 = (const __half2*)&buf[0][i];
                const __half2* h2 = (const __half2*)&buf[1][i];
#pragma unroll
                for (int u = 0; u < 4; ++u) {
                    float2 f1 = __half22float2(h1[u]);
                    float2 f2 = __half22float2(h2[u]);
                    acc0 += f1.x * ps[row][i * 8 + 2 * u] + f1.y * ps[row][i * 8 + 2 * u + 1];
                    acc1 += f2.x * ps[row][i * 8 + 2 * u] + f2.y * ps[row][i * 8 + 2 * u + 1];
                }
            }
            sc[row][l1] = acc0 * INV_SQRT_A;
            sc[row][l2] = acc1 * INV_SQRT_A;
        }
    }
    __syncthreads();

    // ---- Phase B: selection, one row per wave (waves 0-3). R9-proven.
    if (tid < RM * 64) {
        const int w = tid >> 6;
        const int lane = tid & 63;
        const int bb = b0 + w;

        unsigned long long key[16];
#pragma unroll
        for (int j = 0; j < 16; ++j) {
            const int l = j * 64 + lane;
            key[j] = ((unsigned long long)sortable(sc[w][l]) << 10)
                   | (unsigned)(1023 - l);
        }
#pragma unroll
        for (int a = 0; a < 15; ++a)
#pragma unroll
            for (int j = 0; j < 15 - a; ++j) {
                const bool swp = key[j] < key[j + 1];
                const unsigned long long hi = swp ? key[j + 1] : key[j];
                const unsigned long long lo = swp ? key[j] : key[j + 1];
                key[j] = hi; key[j + 1] = lo;
            }

        float myv = -1e30f; int myl = 0;
        unsigned long long front = key[0];
        for (int k = 0; k < TOPK_; ++k) {
            unsigned long long wk = front;
#pragma unroll
            for (int off = 32; off > 0; off >>= 1) {
                unsigned long long o = __shfl_xor(wk, off);
                if (o > wk) wk = o;
            }
            if (lane == k) {
                myv = unsortable((unsigned)(wk >> 10));
                myl = 1023 - (int)(wk & 1023);
            }
            if (front == wk) {
#pragma unroll
                for (int j = 0; j < 15; ++j) key[j] = key[j + 1];
                key[15] = 0ULL;
                front = key[0];
            }
        }

        float m = myv;
#pragma unroll
        for (int off = 32; off > 0; off >>= 1) m = fmaxf(m, __shfl_xor(m, off));
        float e = (lane < TOPK_) ? expf(myv - m) : 0.f;
        float s = e;
#pragma unroll
        for (int off = 32; off > 0; off >>= 1) s += __shfl_xor(s, off);
        if (lane < TOPK_) {
            sw[w][lane]   = e / s;
            stok[w][lane] = seqs[bb * L_ + myl];
        }

        if (lane < E_) {
            float acc = 0.f;
#pragma unroll
            for (int k = 0; k < TOPK_; ++k)
                acc += sw[w][k] * seq_emb[(size_t)stok[w][k] * 32 + lane];
            sc[w][lane] = acc;   // ebar (sc row free now; same-wave r/w)
        }
        if (lane < E_) {
            float acc = bo[lane];
#pragma unroll
            for (int j = 0; j < E_; ++j) acc += sc[w][j] * M[j * E_ + lane];
            fused[bb * 128 + 32 + lane] = acc;   // interest -> global
        }
    }
    __syncthreads();          // all interest stores issued (block-wide)

    // ---- last-man-out: 4th block of the 4-block group runs the 16-row MLP
    if (tid == 0) {
        __threadfence();      // publish this block's fused stores
        const int g = blockIdx.x >> 2;
        const int old = atomicAdd(&cnt[g], 1);
        doml = (old == 3) ? 1 : 0;
        if (old == 3) __threadfence();   // acquire
    }
    __syncthreads();
    if (!doml) return;

    // ================= MFMA MLP for rows r0m .. r0m+15 (R13-proven) =======
    const int r0m = (blockIdx.x >> 2) * GR;
    const int w = tid >> 6;
    const int l = tid & 63;
    const int lr = l & 15;
    const int lk = l >> 4;
    const int n0 = w * 32;

    f32x4 hC0, hC1;
    const f32x4 zf = {0.f, 0.f, 0.f, 0.f};

    // ---- stage 1: h = relu(x @ Wmlp + bmlp), K = 128
    {
        half8 ax[4];
        const float* xrow = fused + (size_t)(r0m + lr) * 128 + lk * 8;
#pragma unroll
        for (int ks = 0; ks < 4; ++ks) {
            float4 u = *(const float4*)(xrow + ks * 32);
            float4 v = *(const float4*)(xrow + ks * 32 + 4);
            ax[ks] = cvt_h8(u, v);
        }
#pragma unroll
        for (int t = 0; t < 2; ++t) {
            f32x4 c = zf;
            const __half* wb = WmlpT + (size_t)(n0 + 16 * t + lr) * 128 + lk * 8;
#pragma unroll
            for (int ks = 0; ks < 4; ++ks) {
                half8 b = *(const half8*)(wb + ks * 32);
                c = __builtin_amdgcn_mfma_f32_16x16x32_f16(ax[ks], b, c, 0, 0, 0);
            }
            const int j = n0 + 16 * t + lr;
            const float bm = bmlp[j];
#pragma unroll
            for (int r = 0; r < 4; ++r) {
                float vv = fmaxf(c[r] + bm, 0.f);
                if (t == 0) hC0[r] = vv; else hC1[r] = vv;
                hs[4 * lk + r][j] = vv;
            }
        }
    }
    __syncthreads();

    // ---- 2 qnn blocks
#pragma unroll
    for (int q = 0; q < 2; ++q) {
        const __half* W1T = q ? W1T2 : W1T1;
        const __half* W2T = q ? W2T2 : W2T1;
        const __half* WpT = q ? WpT2 : WpT1;
        const float* bb1 = q ? b21 : b11;
        const float* bb2 = q ? b22 : b12;
        const float* bbp = q ? b2p : b1p;

        half8 ah[8];
#pragma unroll
        for (int ks = 0; ks < 8; ++ks) {
            const float* hr = &hs[lr][ks * 32 + lk * 8];
            float4 u = *(const float4*)hr;
            float4 v = *(const float4*)(hr + 4);
            ah[ks] = cvt_h8(u, v);
        }
#pragma unroll
        for (int t = 0; t < 2; ++t) {
            f32x4 t1 = zf, t2 = zf;
            const __half* w1 = W1T + (size_t)(n0 + 16 * t + lr) * 256 + lk * 8;
            const __half* w2 = W2T + (size_t)(n0 + 16 * t + lr) * 256 + lk * 8;
#pragma unroll
            for (int ks = 0; ks < 8; ++ks) {
                half8 b1 = *(const half8*)(w1 + ks * 32);
                t1 = __builtin_amdgcn_mfma_f32_16x16x32_f16(ah[ks], b1, t1, 0, 0, 0);
                half8 b2 = *(const half8*)(w2 + ks * 32);
                t2 = __builtin_amdgcn_mfma_f32_16x16x32_f16(ah[ks], b2, t2, 0, 0, 0);
            }
            const int j = n0 + 16 * t + lr;
            const float v1 = bb1[j], v2 = bb2[j];
#pragma unroll
            for (int r = 0; r < 4; ++r) {
                float tv = (t1[r] + v1) * (t2[r] + v2);
                ts_h[4 * lk + r][j] = __float2half_rn(tv);
            }
        }
        __syncthreads();

        half8 pa[8];
#pragma unroll
        for (int ks = 0; ks < 8; ++ks)
            pa[ks] = *(const half8*)&ts_h[lr][ks * 32 + lk * 8];
#pragma unroll
        for (int t = 0; t < 2; ++t) {
            f32x4 c = (t == 0) ? hC0 : hC1;
            const __half* wp = WpT + (size_t)(n0 + 16 * t + lr) * 256 + lk * 8;
#pragma unroll
            for (int ks = 0; ks < 8; ++ks) {
                half8 b = *(const half8*)(wp + ks * 32);
                c = __builtin_amdgcn_mfma_f32_16x16x32_f16(pa[ks], b, c, 0, 0, 0);
            }
            const int j = n0 + 16 * t + lr;
            const float bp = bbp[j];
#pragma unroll
            for (int r = 0; r < 4; ++r) {
                float vv = c[r] + bp;
                if (t == 0) hC0[r] = vv; else hC1[r] = vv;
                hs[4 * lk + r][j] = vv;
            }
        }
        __syncthreads();
    }

    // ---- out = hs @ Wout + bout : 32 threads per row, 8 cols each
    {
        const int i = tid >> 5;
        const int seg = tid & 31;
        const int cb = seg * 8;
        float psum = 0.f;
#pragma unroll
        for (int u = 0; u < 8; ++u) psum += hs[i][cb + u] * Wout[cb + u];
#pragma unroll
        for (int off = 16; off > 0; off >>= 1) psum += __shfl_xor(psum, off);
        if (seg == 0) out[r0m + i] = psum + bout[0];
    }
}

// ---------------------------------------------------------------------------
extern "C" void kernel_launch(void* const* d_in, const int* in_sizes, int n_in,
                              void* d_out, int out_size, void* d_ws, size_t ws_size,
                              hipStream_t stream) {
    const int*   cats    = (const int*)d_in[0];
    const float* nums    = (const float*)d_in[1];
    const int*   seqs    = (const int*)d_in[2];
    const int*   tgt_ids = (const int*)d_in[3];
    const float* cat_emb = (const float*)d_in[4];
    const float* seq_emb = (const float*)d_in[5];
    const float* Wnum    = (const float*)d_in[6];
    const float* bnum    = (const float*)d_in[7];
    const float* Wq      = (const float*)d_in[8];
    const float* Wk      = (const float*)d_in[9];
    const float* Wv      = (const float*)d_in[10];
    const float* Wo      = (const float*)d_in[11];
    const float* bo      = (const float*)d_in[12];
    const float* Wpool   = (const float*)d_in[13];
    const float* bpool   = (const float*)d_in[14];
    const float* Wmlp    = (const float*)d_in[15];
    const float* bmlp    = (const float*)d_in[16];
    const float* q1_W1   = (const float*)d_in[17];
    const float* q1_b1   = (const float*)d_in[18];
    const float* q1_W2   = (const float*)d_in[19];
    const float* q1_b2   = (const float*)d_in[20];
    const float* q1_Wp   = (const float*)d_in[21];
    const float* q1_bp   = (const float*)d_in[22];
    const float* q2_W1   = (const float*)d_in[23];
    const float* q2_b1   = (const float*)d_in[24];
    const float* q2_W2   = (const float*)d_in[25];
    const float* q2_b2   = (const float*)d_in[26];
    const float* q2_Wp   = (const float*)d_in[27];
    const float* q2_bp   = (const float*)d_in[28];
    const float* Wout    = (const float*)d_in[29];
    const float* bout    = (const float*)d_in[30];

    // Workspace layout (float-slot offsets); one half2 == one 4 B slot.
    float* ws = (float*)d_ws;
    float*   p       = ws;                         //      0 .. 32768
    float*   fused   = ws + 32768;                 //  32768 .. 163840
    float*   M       = ws + 163840;                // 163840 .. 164864
    int*     cnt     = (int*)(ws + 164864);        // 164864 .. 164928 (64)
    __half2* seq_h2  = (__half2*)(ws + 164928);    // 164928 .. 964992 (800064)
    __half*  WmlpT   = (__half*)(ws + 964992);     // 964992 .. 981376  (32768 h)
    __half*  W1T1    = (__half*)(ws + 981376);     // 981376 .. 1014144 (65536 h)
    __half*  W2T1    = (__half*)(ws + 1014144);    // 1014144 .. 1046912
    __half*  WpT1    = (__half*)(ws + 1046912);    // 1046912 .. 1079680
    __half*  W1T2    = (__half*)(ws + 1079680);    // 1079680 .. 1112448
    __half*  W2T2    = (__half*)(ws + 1112448);    // 1112448 .. 1145216
    __half*  WpT2    = (__half*)(ws + 1145216);    // 1145216 .. 1177984

    float* out = (float*)d_out;

    fused_prep_kernel<<<K1_GRID, 256, 0, stream>>>(
        cats, nums, tgt_ids, cat_emb, Wnum, bnum, Wq, Wk, Wv, Wo,
        Wpool, bpool, seq_emb, Wmlp,
        q1_W1, q1_W2, q1_Wp, q2_W1, q2_W2, q2_Wp,
        p, fused, M, cnt, seq_h2,
        WmlpT, W1T1, W2T1, WpT1, W1T2, W2T2, WpT2);

    score_mlp_kernel<<<B_ / RM, 512, 0, stream>>>(
        seqs, (const __half*)seq_h2, seq_emb, p, M, bo, fused, cnt,
        WmlpT, bmlp,
        W1T1, W2T1, WpT1, q1_b1, q1_b2, q1_bp,
        W1T2, W2T2, WpT2, q2_b1, q2_b2, q2_bp,
        Wout, bout, out);
}

// Round 5
// 195.708 us; speedup vs baseline: 1.1193x; 1.0183x over previous
//
#include <hip/hip_runtime.h>
#include <hip/hip_fp16.h>

#define B_ 1024
#define L_ 1024
#define NCAT_ 20
#define NNUM_ 10
#define E_ 32
#define A_ 128
#define H_ 256
#define TOPK_ 30
#define INV_SQRT_A 0.08838834764831845f

typedef _Float16 half8 __attribute__((ext_vector_type(8)));
typedef float f32x4 __attribute__((ext_vector_type(4)));

// monotonic float<->u32 (roundtrip exact)
__device__ __forceinline__ unsigned sortable(float f) {
    unsigned u = __float_as_uint(f);
    return (u & 0x80000000u) ? ~u : (u | 0x80000000u);
}
__device__ __forceinline__ float unsortable(unsigned s) {
    unsigned u = (s & 0x80000000u) ? (s ^ 0x80000000u) : ~s;
    return __uint_as_float(u);
}
__device__ __forceinline__ half8 cvt_h8(const float4 u, const float4 v) {
    half8 a;
    a[0] = (_Float16)u.x; a[1] = (_Float16)u.y;
    a[2] = (_Float16)u.z; a[3] = (_Float16)u.w;
    a[4] = (_Float16)v.x; a[5] = (_Float16)v.y;
    a[6] = (_Float16)v.z; a[7] = (_Float16)v.w;
    return a;
}

// ---------------------------------------------------------------------------
// K1: prep + seq f16 conversion + M + weight transpose.  Grid 1356 (as R0).
//  blk <  256 : per-4-row prep (fused cols 0-31/64-127, p = q@Wk^T)
//  blk < 1280 : seq_emb -> f16 (3.2 MB table => L2-resident gathers in K2;
//               R13 proved f32 gathers thrash the 4 MB/XCD L2: FETCH 20->69MB)
//  blk < 1284 : M = Wv@Wo fold
//  blk < 1356 : transposed f16 weights WT[n][k] for the MFMA MLP
// ---------------------------------------------------------------------------
#define K1_GRID 1356
__global__ __launch_bounds__(256) void fused_prep_kernel(
    const int* __restrict__ cats, const float* __restrict__ nums,
    const int* __restrict__ tgt_ids, const float* __restrict__ cat_emb,
    const float* __restrict__ Wnum, const float* __restrict__ bnum,
    const float* __restrict__ Wq, const float* __restrict__ Wk,
    const float* __restrict__ Wv, const float* __restrict__ Wo,
    const float* __restrict__ Wpool, const float* __restrict__ bpool,
    const float* __restrict__ seq_emb, const float* __restrict__ Wmlp,
    const float* __restrict__ q1W1, const float* __restrict__ q1W2,
    const float* __restrict__ q1Wp,
    const float* __restrict__ q2W1, const float* __restrict__ q2W2,
    const float* __restrict__ q2Wp,
    float* __restrict__ p_out, float* __restrict__ fused, float* __restrict__ M,
    __half2* __restrict__ seq_h2,
    __half* __restrict__ WmlpT,
    __half* __restrict__ W1T1, __half* __restrict__ W2T1, __half* __restrict__ WpT1,
    __half* __restrict__ W1T2, __half* __restrict__ W2T2, __half* __restrict__ WpT2)
{
    const int blk = blockIdx.x;
    const int t = threadIdx.x;

    if (blk < 256) {
        __shared__ float ce[4][NCAT_ * E_];
        __shared__ float tg[4][E_];
        __shared__ float nm[4][NNUM_];
        __shared__ float qs[4][A_];
        __shared__ float part[8][4][E_];
        const int r0 = blk * 4;

        for (int idx = t; idx < 640; idx += 256) {
            const int q = idx >> 3, f4 = idx & 7;
            const int row = q / 20, cat = q % 20;
            const int tok = cats[(r0 + row) * NCAT_ + cat];
            ((float4*)&ce[row][cat * 32])[f4] =
                ((const float4*)(cat_emb + (size_t)tok * 32))[f4];
        }
        if (t < 32) {
            const int row = t >> 3, f4 = t & 7;
            const int tok = tgt_ids[r0 + row];
            ((float4*)&tg[row][0])[f4] =
                ((const float4*)(cat_emb + (size_t)tok * 32))[f4];
        }
        if (t >= 64 && t < 104) {
            const int x = t - 64;
            nm[x / 10][x % 10] = nums[(r0 + x / 10) * NNUM_ + x % 10];
        }
        __syncthreads();

        {
            const int w = t >> 6, lane = t & 63;
            float q0 = 0.f, q1 = 0.f;
#pragma unroll
            for (int e = 0; e < E_; ++e) {
                float te = tg[w][e];
                q0 += te * Wq[e * A_ + lane];
                q1 += te * Wq[e * A_ + lane + 64];
            }
            qs[w][lane] = q0; qs[w][lane + 64] = q1;
        }

        {
            const int iseg = t >> 5;
            const int row = (t >> 3) & 3;
            const int c0 = (t & 7) * 4;
            float4 acc = make_float4(0.f, 0.f, 0.f, 0.f);
            const int i0 = iseg * 80;
            for (int i = i0; i < i0 + 80; ++i) {
                float4 wv = *(const float4*)(Wpool + i * 32 + c0);
                acc.x += ce[row][i] * wv.x; acc.y += ce[row][i] * wv.y;
                acc.z += ce[row][i] * wv.z; acc.w += ce[row][i] * wv.w;
            }
            *(float4*)&part[iseg][row][c0] = acc;
        }
        __syncthreads();

        if (t < 128) {
            const int row = t >> 5, c = t & 31;
            const int b = r0 + row;
            float s = bpool[c];
#pragma unroll
            for (int g = 0; g < 8; ++g) s += part[g][row][c];
            fused[b * 128 + 64 + c] = s;
            fused[b * 128 + c] = tg[row][c];

            float ne = bnum[c];
#pragma unroll
            for (int n = 0; n < NNUM_; ++n) ne += nm[row][n] * Wnum[n * 32 + c];
            fused[b * 128 + 96 + c] = ne;

            float pv = 0.f;
#pragma unroll 8
            for (int a = 0; a < A_; ++a) pv += Wk[c * A_ + a] * qs[row][a];
            p_out[b * 32 + c] = pv;
        }
        return;
    }

    if (blk < 1280) {
        int x = (blk - 256) * 256 + t;
        for (; x < 800016; x += 1024 * 256) {
            float2 v = ((const float2*)seq_emb)[x];
            seq_h2[x] = __float22half2_rn(v);
        }
        return;
    }

    if (blk < 1284) {
        const int o = (blk - 1280) * 256 + t;
        const int j = o >> 5, e = o & 31;
        float sm = 0.f;
#pragma unroll 8
        for (int a = 0; a < A_; ++a) sm += Wv[j * A_ + a] * Wo[a * E_ + e];
        M[o] = sm;
        return;
    }

    // ---- transpose-convert weights to [n][k] f16 (blocks 1284..1355)
    {
        int c = (blk - 1284) * 256 + t;           // 0 .. 18431
        for (; c < 53248; c += 72 * 256) {
            const float* src; __half* dst;
            int n, k0, K;
            if (c < 4096) {
                n = c >> 4; k0 = (c & 15) << 3; K = 128;
                src = Wmlp; dst = WmlpT;
            } else {
                const int c2 = c - 4096;
                const int m = c2 >> 13, idx = c2 & 8191;
                n = idx >> 5; k0 = (idx & 31) << 3; K = 256;
                switch (m) {
                    case 0: src = q1W1; dst = W1T1; break;
                    case 1: src = q1W2; dst = W2T1; break;
                    case 2: src = q1Wp; dst = WpT1; break;
                    case 3: src = q2W1; dst = W1T2; break;
                    case 4: src = q2W2; dst = W2T2; break;
                    default: src = q2Wp; dst = WpT2; break;
                }
            }
            float v[8];
#pragma unroll
            for (int i = 0; i < 8; ++i) v[i] = src[(size_t)(k0 + i) * 256 + n];
            float4 wq;
            __half2* hp = (__half2*)&wq;
            hp[0] = __float22half2_rn(make_float2(v[0], v[1]));
            hp[1] = __float22half2_rn(make_float2(v[2], v[3]));
            hp[2] = __float22half2_rn(make_float2(v[4], v[5]));
            hp[3] = __float22half2_rn(make_float2(v[6], v[7]));
            *(float4*)(dst + (size_t)n * K + k0) = wq;
        }
    }
}

// ---------------------------------------------------------------------------
// K2: scores (f16 gathers) + top-30 + softmax + interest (R0-proven A+B),
// then Phase C as in-block MFMA MLP: every block computes its OWN 4 rows,
// replicated x4 into the M=16 tile (row = b0 + (lr&3)); rows 4-15 of every
// fragment are duplicates, discarded at the epilogue.  MFMA pipe is ~free
// (0.4% util at 64 blocks), so 4x redundancy costs nothing; what we save is
// the GEMV chain's per-element cvt+FMA VALU tax (~10-15 us in R0).
// Interest stays in LDS (xs) - no global round-trip.  No extra launches,
// no idle-tail (R14's mistake), no inter-block sync.
// ---------------------------------------------------------------------------
#define RM 4
#define GR 16
#define HSP 260
#define TSP 264
#define XSP 132
__global__ __launch_bounds__(512) void score_mlp_kernel(
    const int* __restrict__ seqs, const __half* __restrict__ seq_h,
    const float* __restrict__ seq_emb, const float* __restrict__ p,
    const float* __restrict__ M, const float* __restrict__ bo,
    const float* __restrict__ fused,
    const __half* __restrict__ WmlpT, const float* __restrict__ bmlp,
    const __half* __restrict__ W1T1, const __half* __restrict__ W2T1,
    const __half* __restrict__ WpT1,
    const float* __restrict__ b11, const float* __restrict__ b12,
    const float* __restrict__ b1p,
    const __half* __restrict__ W1T2, const __half* __restrict__ W2T2,
    const __half* __restrict__ WpT2,
    const float* __restrict__ b21, const float* __restrict__ b22,
    const float* __restrict__ b2p,
    const float* __restrict__ Wout, const float* __restrict__ bout,
    float* __restrict__ out)
{
    const int b0 = blockIdx.x * RM;
    const int tid = threadIdx.x;

    __shared__ float sc[RM][L_];          // 16 KB (score rows; reused as ebar)
    __shared__ float ps[RM][E_];
    __shared__ float sw[RM][32];
    __shared__ int   stok[RM][32];
    __shared__ float xs[RM][XSP];         // x rows (tgt|interest|pool|num)
    __shared__ float hs[GR][HSP];         // MFMA activations (f32)
    __shared__ __half ts_h[GR][TSP];      // quad term (f16)

    if (tid < RM * 32)
        ps[tid >> 5][tid & 31] = p[(b0 + (tid >> 5)) * 32 + (tid & 31)];
    __syncthreads();

    // ---- Phase A: scores (f16 table, L2-resident). 128 thr/row, 8 tok/thr
    {
        const int row = tid >> 7;
        const int s = tid & 127;
        const int bb = b0 + row;
#pragma unroll
        for (int jj = 0; jj < 4; ++jj) {
            const int l1 = jj * 256 + s;
            const int l2 = l1 + 128;
            const int tok1 = seqs[bb * L_ + l1];
            const int tok2 = seqs[bb * L_ + l2];
            float4 buf[2][4];
            const float4* r1 = (const float4*)(seq_h + (size_t)tok1 * 32);
            const float4* r2 = (const float4*)(seq_h + (size_t)tok2 * 32);
#pragma unroll
            for (int i = 0; i < 4; ++i) buf[0][i] = r1[i];
#pragma unroll
            for (int i = 0; i < 4; ++i) buf[1][i] = r2[i];

            float acc0 = 0.f, acc1 = 0.f;
#pragma unroll
            for (int i = 0; i < 4; ++i) {
                const __half2* h1 = (const __half2*)&buf[0][i];
                const __half2* h2 = (const __half2*)&buf[1][i];
#pragma unroll
                for (int u = 0; u < 4; ++u) {
                    float2 f1 = __half22float2(h1[u]);
                    float2 f2 = __half22float2(h2[u]);
                    acc0 += f1.x * ps[row][i * 8 + 2 * u] + f1.y * ps[row][i * 8 + 2 * u + 1];
                    acc1 += f2.x * ps[row][i * 8 + 2 * u] + f2.y * ps[row][i * 8 + 2 * u + 1];
                }
            }
            sc[row][l1] = acc0 * INV_SQRT_A;
            sc[row][l2] = acc1 * INV_SQRT_A;
        }
    }
    // xs cols 0-31 and 64-127 from K1's fused (interest cols filled in B)
    if (tid < 384) {
        const int r = tid / 96, c0 = tid % 96;
        const int c = (c0 < 32) ? c0 : (c0 + 32);
        xs[r][c] = fused[(b0 + r) * 128 + c];
    }
    __syncthreads();

    // ---- Phase B: selection, one row per wave (waves 0-3). R9-proven.
    if (tid < RM * 64) {
        const int w = tid >> 6;
        const int lane = tid & 63;
        const int bb = b0 + w;

        unsigned long long key[16];
#pragma unroll
        for (int j = 0; j < 16; ++j) {
            const int l = j * 64 + lane;
            key[j] = ((unsigned long long)sortable(sc[w][l]) << 10)
                   | (unsigned)(1023 - l);
        }
#pragma unroll
        for (int a = 0; a < 15; ++a)
#pragma unroll
            for (int j = 0; j < 15 - a; ++j) {
                const bool swp = key[j] < key[j + 1];
                const unsigned long long hi = swp ? key[j + 1] : key[j];
                const unsigned long long lo = swp ? key[j] : key[j + 1];
                key[j] = hi; key[j + 1] = lo;
            }

        float myv = -1e30f; int myl = 0;
        unsigned long long front = key[0];
        for (int k = 0; k < TOPK_; ++k) {
            unsigned long long wk = front;
#pragma unroll
            for (int off = 32; off > 0; off >>= 1) {
                unsigned long long o = __shfl_xor(wk, off);
                if (o > wk) wk = o;
            }
            if (lane == k) {
                myv = unsortable((unsigned)(wk >> 10));
                myl = 1023 - (int)(wk & 1023);
            }
            if (front == wk) {
#pragma unroll
                for (int j = 0; j < 15; ++j) key[j] = key[j + 1];
                key[15] = 0ULL;
                front = key[0];
            }
        }

        float m = myv;
#pragma unroll
        for (int off = 32; off > 0; off >>= 1) m = fmaxf(m, __shfl_xor(m, off));
        float e = (lane < TOPK_) ? expf(myv - m) : 0.f;
        float s = e;
#pragma unroll
        for (int off = 32; off > 0; off >>= 1) s += __shfl_xor(s, off);
        if (lane < TOPK_) {
            sw[w][lane]   = e / s;
            stok[w][lane] = seqs[bb * L_ + myl];
        }

        if (lane < E_) {
            float acc = 0.f;
#pragma unroll
            for (int k = 0; k < TOPK_; ++k)
                acc += sw[w][k] * seq_emb[(size_t)stok[w][k] * 32 + lane];
            sc[w][lane] = acc;   // ebar (sc row free now; same-wave r/w)
        }
        if (lane < E_) {
            float acc = bo[lane];
#pragma unroll
            for (int j = 0; j < E_; ++j) acc += sc[w][j] * M[j * E_ + lane];
            xs[w][32 + lane] = acc;   // interest -> LDS only
        }
    }
    __syncthreads();

    // ================= Phase C: MFMA MLP, rows b0..b0+3 (x4 replicated) ====
    const int w = tid >> 6;
    const int l = tid & 63;
    const int lr = l & 15;
    const int lk = l >> 4;
    const int n0 = w * 32;

    f32x4 hC0, hC1;
    const f32x4 zf = {0.f, 0.f, 0.f, 0.f};

    // ---- stage 1: h = relu(x @ Wmlp + bmlp), K = 128.  A row lr -> xs[lr&3]
    {
        half8 ax[4];
        const float* xrow = &xs[lr & 3][lk * 8];
#pragma unroll
        for (int ks = 0; ks < 4; ++ks) {
            float4 u = *(const float4*)(xrow + ks * 32);
            float4 v = *(const float4*)(xrow + ks * 32 + 4);
            ax[ks] = cvt_h8(u, v);
        }
#pragma unroll
        for (int t = 0; t < 2; ++t) {
            f32x4 c = zf;
            const __half* wb = WmlpT + (size_t)(n0 + 16 * t + lr) * 128 + lk * 8;
#pragma unroll
            for (int ks = 0; ks < 4; ++ks) {
                half8 b = *(const half8*)(wb + ks * 32);
                c = __builtin_amdgcn_mfma_f32_16x16x32_f16(ax[ks], b, c, 0, 0, 0);
            }
            const int j = n0 + 16 * t + lr;
            const float bm = bmlp[j];
#pragma unroll
            for (int r = 0; r < 4; ++r) {
                float vv = fmaxf(c[r] + bm, 0.f);
                if (t == 0) hC0[r] = vv; else hC1[r] = vv;
                hs[4 * lk + r][j] = vv;
            }
        }
    }
    __syncthreads();

    // ---- 2 qnn blocks
#pragma unroll
    for (int q = 0; q < 2; ++q) {
        const __half* W1T = q ? W1T2 : W1T1;
        const __half* W2T = q ? W2T2 : W2T1;
        const __half* WpT = q ? WpT2 : WpT1;
        const float* bb1 = q ? b21 : b11;
        const float* bb2 = q ? b22 : b12;
        const float* bbp = q ? b2p : b1p;

        half8 ah[8];
#pragma unroll
        for (int ks = 0; ks < 8; ++ks) {
            const float* hr = &hs[lr][ks * 32 + lk * 8];
            float4 u = *(const float4*)hr;
            float4 v = *(const float4*)(hr + 4);
            ah[ks] = cvt_h8(u, v);
        }
#pragma unroll
        for (int t = 0; t < 2; ++t) {
            f32x4 t1 = zf, t2 = zf;
            const __half* w1 = W1T + (size_t)(n0 + 16 * t + lr) * 256 + lk * 8;
            const __half* w2 = W2T + (size_t)(n0 + 16 * t + lr) * 256 + lk * 8;
#pragma unroll
            for (int ks = 0; ks < 8; ++ks) {
                half8 b1 = *(const half8*)(w1 + ks * 32);
                t1 = __builtin_amdgcn_mfma_f32_16x16x32_f16(ah[ks], b1, t1, 0, 0, 0);
                half8 b2 = *(const half8*)(w2 + ks * 32);
                t2 = __builtin_amdgcn_mfma_f32_16x16x32_f16(ah[ks], b2, t2, 0, 0, 0);
            }
            const int j = n0 + 16 * t + lr;
            const float v1 = bb1[j], v2 = bb2[j];
#pragma unroll
            for (int r = 0; r < 4; ++r) {
                float tv = (t1[r] + v1) * (t2[r] + v2);
                ts_h[4 * lk + r][j] = __float2half_rn(tv);
            }
        }
        __syncthreads();

        half8 pa[8];
#pragma unroll
        for (int ks = 0; ks < 8; ++ks)
            pa[ks] = *(const half8*)&ts_h[lr][ks * 32 + lk * 8];
#pragma unroll
        for (int t = 0; t < 2; ++t) {
            f32x4 c = (t == 0) ? hC0 : hC1;
            const __half* wp = WpT + (size_t)(n0 + 16 * t + lr) * 256 + lk * 8;
#pragma unroll
            for (int ks = 0; ks < 8; ++ks) {
                half8 b = *(const half8*)(wp + ks * 32);
                c = __builtin_amdgcn_mfma_f32_16x16x32_f16(pa[ks], b, c, 0, 0, 0);
            }
            const int j = n0 + 16 * t + lr;
            const float bp = bbp[j];
#pragma unroll
            for (int r = 0; r < 4; ++r) {
                float vv = c[r] + bp;
                if (t == 0) hC0[r] = vv; else hC1[r] = vv;
                hs[4 * lk + r][j] = vv;
            }
        }
        __syncthreads();
    }

    // ---- out = hs @ Wout + bout, rows 0-3 only (4-15 are duplicates)
    if (tid < 128) {
        const int i = tid >> 5;           // 0..3
        const int seg = tid & 31;
        const int cb = seg * 8;
        float psum = 0.f;
#pragma unroll
        for (int u = 0; u < 8; ++u) psum += hs[i][cb + u] * Wout[cb + u];
#pragma unroll
        for (int off = 16; off > 0; off >>= 1) psum += __shfl_xor(psum, off);
        if (seg == 0) out[b0 + i] = psum + bout[0];
    }
}

// ---------------------------------------------------------------------------
extern "C" void kernel_launch(void* const* d_in, const int* in_sizes, int n_in,
                              void* d_out, int out_size, void* d_ws, size_t ws_size,
                              hipStream_t stream) {
    const int*   cats    = (const int*)d_in[0];
    const float* nums    = (const float*)d_in[1];
    const int*   seqs    = (const int*)d_in[2];
    const int*   tgt_ids = (const int*)d_in[3];
    const float* cat_emb = (const float*)d_in[4];
    const float* seq_emb = (const float*)d_in[5];
    const float* Wnum    = (const float*)d_in[6];
    const float* bnum    = (const float*)d_in[7];
    const float* Wq      = (const float*)d_in[8];
    const float* Wk      = (const float*)d_in[9];
    const float* Wv      = (const float*)d_in[10];
    const float* Wo      = (const float*)d_in[11];
    const float* bo      = (const float*)d_in[12];
    const float* Wpool   = (const float*)d_in[13];
    const float* bpool   = (const float*)d_in[14];
    const float* Wmlp    = (const float*)d_in[15];
    const float* bmlp    = (const float*)d_in[16];
    const float* q1_W1   = (const float*)d_in[17];
    const float* q1_b1   = (const float*)d_in[18];
    const float* q1_W2   = (const float*)d_in[19];
    const float* q1_b2   = (const float*)d_in[20];
    const float* q1_Wp   = (const float*)d_in[21];
    const float* q1_bp   = (const float*)d_in[22];
    const float* q2_W1   = (const float*)d_in[23];
    const float* q2_b1   = (const float*)d_in[24];
    const float* q2_W2   = (const float*)d_in[25];
    const float* q2_b2   = (const float*)d_in[26];
    const float* q2_Wp   = (const float*)d_in[27];
    const float* q2_bp   = (const float*)d_in[28];
    const float* Wout    = (const float*)d_in[29];
    const float* bout    = (const float*)d_in[30];

    // Workspace layout (float-slot offsets); one half2 == one 4 B slot.
    float* ws = (float*)d_ws;
    float*   p       = ws;                         //      0 .. 32768
    float*   fused   = ws + 32768;                 //  32768 .. 163840
    float*   M       = ws + 163840;                // 163840 .. 164864
    __half2* seq_h2  = (__half2*)(ws + 164928);    // 164928 .. 964992 (800064)
    __half*  WmlpT   = (__half*)(ws + 964992);     // 964992 .. 981376  (32768 h)
    __half*  W1T1    = (__half*)(ws + 981376);     // 981376 .. 1014144 (65536 h)
    __half*  W2T1    = (__half*)(ws + 1014144);    // 1014144 .. 1046912
    __half*  WpT1    = (__half*)(ws + 1046912);    // 1046912 .. 1079680
    __half*  W1T2    = (__half*)(ws + 1079680);    // 1079680 .. 1112448
    __half*  W2T2    = (__half*)(ws + 1112448);    // 1112448 .. 1145216
    __half*  WpT2    = (__half*)(ws + 1145216);    // 1145216 .. 1177984

    float* out = (float*)d_out;

    fused_prep_kernel<<<K1_GRID, 256, 0, stream>>>(
        cats, nums, tgt_ids, cat_emb, Wnum, bnum, Wq, Wk, Wv, Wo,
        Wpool, bpool, seq_emb, Wmlp,
        q1_W1, q1_W2, q1_Wp, q2_W1, q2_W2, q2_Wp,
        p, fused, M, seq_h2,
        WmlpT, W1T1, W2T1, WpT1, W1T2, W2T2, WpT2);

    score_mlp_kernel<<<B_ / RM, 512, 0, stream>>>(
        seqs, (const __half*)seq_h2, seq_emb, p, M, bo, fused,
        WmlpT, bmlp,
        W1T1, W2T1, WpT1, q1_b1, q1_b2, q1_bp,
        W1T2, W2T2, WpT2, q2_b1, q2_b2, q2_bp,
        Wout, bout, out);
}